// Round 11
// baseline (277.505 us; speedup 1.0000x reference)
//
#include <hip/hip_runtime.h>
#include <hip/hip_bf16.h>

#define TOKENS (16*1024)
#define HD 512
#define MM 2048
#define TB 16   // tokens per stage_a block

typedef short s16x8 __attribute__((ext_vector_type(8)));
typedef float f32x4 __attribute__((ext_vector_type(4)));

__device__ __forceinline__ __hip_bfloat16 f2bf(float v){ return __float2bfloat16(v); }
__device__ __forceinline__ unsigned short f2bfu(float v){
  __hip_bfloat16 b = __float2bfloat16(v);
  unsigned short u; __builtin_memcpy(&u, &b, 2); return u;
}
__device__ __forceinline__ float bfu2f(unsigned short u){
  unsigned int x = ((unsigned int)u) << 16; float f; __builtin_memcpy(&f, &x, 4); return f;
}
__device__ __forceinline__ float bfx(uint2 p, int r){
  unsigned int u = (r & 2) ? p.y : p.x;
  u = (r & 1) ? (u & 0xffff0000u) : (u << 16);
  float f; __builtin_memcpy(&f, &u, 4); return f;
}
__device__ __forceinline__ uint2 packbf4(float a, float b, float c, float d){
  uint2 o;
  o.x = (unsigned)f2bfu(a) | ((unsigned)f2bfu(b) << 16);
  o.y = (unsigned)f2bfu(c) | ((unsigned)f2bfu(d) << 16);
  return o;
}
__device__ __forceinline__ uint4 pack8(const float* v){
  unsigned short s[8];
  #pragma unroll
  for (int e = 0; e < 8; e++) s[e] = f2bfu(v[e]);
  uint4 u; __builtin_memcpy(&u, s, 16); return u;
}
__device__ __forceinline__ void unpack8(uint4 u, float* v){
  const unsigned short* s = (const unsigned short*)&u;
  #pragma unroll
  for (int e = 0; e < 8; e++) v[e] = bfu2f(s[e]);
}

// async global->LDS, 16B per lane (GEMM staging)
typedef const __attribute__((address_space(1))) unsigned int* gas_t;
typedef __attribute__((address_space(3))) unsigned int* las_t;
__device__ __forceinline__ void async16(const void* g, void* l){
  __builtin_amdgcn_global_load_lds((gas_t)g, (las_t)l, 16, 0, 0);
}

#define SWZ(t) (((t) & 7) << 4)             // Xa byte-address swizzle
#define QSCALE 0.18033688011112042f         // 0.125 * log2(e)

// ---- register-resident 8x8 criss-cross attention; writes result (bf16) to Xa dst ----
__device__ __forceinline__ void attn_reg(const uint2* qp, const uint2* kp, const uint2* vp,
                                         unsigned char* XaDst, int wave, int lane)
{
  const int lr = lane & 15, lg = lane >> 4;
  #pragma unroll
  for (int r = 0; r < 4; r++){
    const int t = lg*4 + r;
    float qq[8], kk[8], vv[8];
    #pragma unroll
    for (int m = 0; m < 8; m++){ qq[m] = bfx(qp[m], r); kk[m] = bfx(kp[m], r); vv[m] = bfx(vp[m], r); }
    float ou[8];
    #pragma unroll
    for (int m = 0; m < 8; m++) ou[m] = 0.f;
    #pragma unroll
    for (int c = 0; c < 8; c++){
      float er[8], den = 0.f;
      #pragma unroll
      for (int m = 0; m < 8; m++){ er[m] = exp2f(qq[c] * kk[m]); den += er[m]; }
      float wc = __fdividef(vv[c], den);
      #pragma unroll
      for (int m = 0; m < 8; m++) ou[m] += wc * er[m];
    }
    #pragma unroll
    for (int m = 0; m < 8; m++){
      int addr = (((m*16 + t)*64 + wave*16 + lr)*2) ^ SWZ(t);
      *(unsigned short*)(XaDst + addr) = f2bfu(ou[m]);
    }
  }
}

// ---- one 16x16 MFMA pair over K=64: A from Xa channel c, B = global bf16 row ----
__device__ __forceinline__ f32x4 proj_tile(const unsigned char* Xa, int c,
                                           const __hip_bfloat16* Brow, int lr, int lg)
{
  const int abase = (c*16 + lr)*128;
  s16x8 af0 = *(const s16x8*)(Xa + ((abase + lg*16) ^ SWZ(lr)));
  s16x8 af1 = *(const s16x8*)(Xa + ((abase + 64 + lg*16) ^ SWZ(lr)));
  s16x8 b0 = *(const s16x8*)((const void*)(Brow + lg*8));
  s16x8 b1 = *(const s16x8*)((const void*)(Brow + 32 + lg*8));
  f32x4 acc = {0.f,0.f,0.f,0.f};
  acc = __builtin_amdgcn_mfma_f32_16x16x32_bf16(af0, b0, acc, 0, 0, 0);
  acc = __builtin_amdgcn_mfma_f32_16x16x32_bf16(af1, b1, acc, 0, 0, 0);
  return acc;
}

// r11: live-state diet so the (256,4) 128-reg/wave unified budget fits:
//  - xc[8] (32 regs) removed: fc_c staged bf16 in XaB, LN3 fused into the flush
//  - cv[4][8] (32 regs) removed: ctx written to XaB BEFORE q-proj (XaB free post-B_D)
// r9 (256,2): VGPR=108, no spill, occ 19%, 115us.  r10 (256,4): spill, 141us.
__global__ __launch_bounds__(256, 4)
void fused_stage_a(const float* __restrict__ x, const float* __restrict__ ctx,
                   const float* __restrict__ ln1w, const float* __restrict__ ln1b,
                   const __hip_bfloat16* __restrict__ qkvT, const float* __restrict__ b_qkv,
                   const __hip_bfloat16* __restrict__ fcsT, const float* __restrict__ b_fcs,
                   const float* __restrict__ ln2w, const float* __restrict__ ln2b,
                   const __hip_bfloat16* __restrict__ qT, const float* __restrict__ b_q,
                   const __hip_bfloat16* __restrict__ kvT, const float* __restrict__ b_kv,
                   const __hip_bfloat16* __restrict__ fccT, const float* __restrict__ b_fcc,
                   const float* __restrict__ ln3w, const float* __restrict__ ln3b,
                   float* __restrict__ xca_out, __hip_bfloat16* __restrict__ y_out)
{
  __shared__ __align__(16) unsigned char XaA[16384];  // [8c][16t][64k] bf16, swizzled
  __shared__ __align__(16) unsigned char XaB[16384];  // attn1 out / ctx / fc_c staging
  __shared__ float sred[4][16][2];

  const int tid = threadIdx.x, lane = tid & 63, wave = tid >> 6;
  const int lr = lane & 15, lg = lane >> 4;
  const int d  = wave*16 + lr;                 // this thread's column slice (within 64)
  const size_t tokbase = (size_t)blockIdx.x * TB;
  const size_t rowbase = (tokbase + lg*4) * HD;
  const int cW = lane >> 3, k0W = (lane & 7) * 8;   // row-loader Xa write slot

  // ---------------- phase 1: LN1(x) -> XaA (vectorized row loads) ----------------
  {
    float lw[8], lb[8];
    {
      float4 w0 = *(const float4*)(ln1w + lane*8), w1 = *(const float4*)(ln1w + lane*8 + 4);
      float4 c0 = *(const float4*)(ln1b + lane*8), c1 = *(const float4*)(ln1b + lane*8 + 4);
      lw[0]=w0.x; lw[1]=w0.y; lw[2]=w0.z; lw[3]=w0.w; lw[4]=w1.x; lw[5]=w1.y; lw[6]=w1.z; lw[7]=w1.w;
      lb[0]=c0.x; lb[1]=c0.y; lb[2]=c0.z; lb[3]=c0.w; lb[4]=c1.x; lb[5]=c1.y; lb[6]=c1.z; lb[7]=c1.w;
    }
    #pragma unroll
    for (int tt = 0; tt < 4; tt++){
      int t = wave * 4 + tt;
      const float* xr = x + (tokbase + t) * HD + lane * 8;
      float v[8];
      float4 a0 = *(const float4*)xr, a1 = *(const float4*)(xr + 4);
      v[0]=a0.x; v[1]=a0.y; v[2]=a0.z; v[3]=a0.w; v[4]=a1.x; v[5]=a1.y; v[6]=a1.z; v[7]=a1.w;
      float sm = 0.f, sq = 0.f;
      #pragma unroll
      for (int e = 0; e < 8; e++){ sm += v[e]; sq += v[e]*v[e]; }
      #pragma unroll
      for (int o = 32; o > 0; o >>= 1){ sm += __shfl_xor(sm, o); sq += __shfl_xor(sq, o); }
      float mu = sm * (1.f/512.f), rs = rsqrtf(sq * (1.f/512.f) - mu*mu + 1e-6f);
      float nv[8];
      #pragma unroll
      for (int e = 0; e < 8; e++) nv[e] = (v[e]-mu)*rs*lw[e] + lb[e];
      *(uint4*)(XaA + ((((cW*16 + t)*64 + k0W)*2) ^ SWZ(t))) = pack8(nv);
    }
  }
  __syncthreads();                                           // B_A

  // ---------------- phase 2: qkv proj -> regs; attention #1 -> XaB ----------------
  {
    uint2 qp[8], kp[8], vp[8];
    #pragma unroll
    for (int c = 0; c < 8; c++){
      const int abase = (c*16 + lr)*128;
      s16x8 af0 = *(const s16x8*)(XaA + ((abase + lg*16) ^ SWZ(lr)));
      s16x8 af1 = *(const s16x8*)(XaA + ((abase + 64 + lg*16) ^ SWZ(lr)));
      const __hip_bfloat16* wr_ = qkvT + ((size_t)c*192 + d)*64;
      f32x4 aq = {0.f,0.f,0.f,0.f}, ak = aq, av = aq;
      aq = __builtin_amdgcn_mfma_f32_16x16x32_bf16(af0, *(const s16x8*)((const void*)(wr_ + lg*8)), aq,0,0,0);
      aq = __builtin_amdgcn_mfma_f32_16x16x32_bf16(af1, *(const s16x8*)((const void*)(wr_ + 32 + lg*8)), aq,0,0,0);
      ak = __builtin_amdgcn_mfma_f32_16x16x32_bf16(af0, *(const s16x8*)((const void*)(wr_ + 64*64 + lg*8)), ak,0,0,0);
      ak = __builtin_amdgcn_mfma_f32_16x16x32_bf16(af1, *(const s16x8*)((const void*)(wr_ + 64*64 + 32 + lg*8)), ak,0,0,0);
      av = __builtin_amdgcn_mfma_f32_16x16x32_bf16(af0, *(const s16x8*)((const void*)(wr_ + 128*64 + lg*8)), av,0,0,0);
      av = __builtin_amdgcn_mfma_f32_16x16x32_bf16(af1, *(const s16x8*)((const void*)(wr_ + 128*64 + 32 + lg*8)), av,0,0,0);
      float bq = b_qkv[c*192 + d], bk = b_qkv[c*192 + 64 + d], bv = b_qkv[c*192 + 128 + d];
      qp[c] = packbf4((aq[0]+bq)*QSCALE, (aq[1]+bq)*QSCALE, (aq[2]+bq)*QSCALE, (aq[3]+bq)*QSCALE);
      kp[c] = packbf4(ak[0]+bk, ak[1]+bk, ak[2]+bk, ak[3]+bk);
      vp[c] = packbf4(av[0]+bv, av[1]+bv, av[2]+bv, av[3]+bv);
    }
    attn_reg(qp, kp, vp, XaB, wave, lane);
  }
  __syncthreads();                                           // B_B

  // ---------------- phase 4: fc_s (XaB) + residual (re-read XaA) + LN2 -> XaA ----------------
  {
    f32x4 fs[8];
    const __hip_bfloat16* br = fcsT + (size_t)d*64;
    const float bb = b_fcs[d];
    #pragma unroll
    for (int c = 0; c < 8; c++) fs[c] = proj_tile(XaB, c, br, lr, lg);
    float val[8][4];
    #pragma unroll
    for (int c = 0; c < 8; c++)
      #pragma unroll
      for (int r = 0; r < 4; r++){
        int t = lg*4 + r;
        float xin = bfu2f(*(const unsigned short*)(XaA + ((((c*16 + t)*64 + d)*2) ^ SWZ(t))));
        val[c][r] = fs[c][r] + bb + xin;
      }
    float lw[8], lb[8];
    #pragma unroll
    for (int c = 0; c < 8; c++){ lw[c] = ln2w[c*64 + d]; lb[c] = ln2b[c*64 + d]; }
    #pragma unroll
    for (int r = 0; r < 4; r++){
      float sm = 0.f, sq = 0.f;
      #pragma unroll
      for (int c = 0; c < 8; c++){ sm += val[c][r]; sq += val[c][r]*val[c][r]; }
      #pragma unroll
      for (int o = 8; o > 0; o >>= 1){ sm += __shfl_xor(sm, o); sq += __shfl_xor(sq, o); }
      if (lr == 0){ sred[wave][lg*4+r][0] = sm; sred[wave][lg*4+r][1] = sq; }
    }
    __syncthreads();                                         // B_C
    #pragma unroll
    for (int r = 0; r < 4; r++){
      int t = lg*4 + r;
      float S = sred[0][t][0]+sred[1][t][0]+sred[2][t][0]+sred[3][t][0];
      float Q = sred[0][t][1]+sred[1][t][1]+sred[2][t][1]+sred[3][t][1];
      float mu = S * (1.f/512.f);
      float rs = rsqrtf(Q * (1.f/512.f) - mu*mu + 1e-6f);
      #pragma unroll
      for (int c = 0; c < 8; c++)
        *(unsigned short*)(XaA + ((((c*16 + t)*64 + d)*2) ^ SWZ(t))) =
            f2bfu((val[c][r]-mu)*rs*lw[c] + lb[c]);
    }
  }
  __syncthreads();                                           // B_D

  // ---------------- phase 6: ctx -> XaB (XaB free post-B_D) ; then q proj -> regs ----------------
  uint2 qp2[8];
  {
    #pragma unroll
    for (int tt = 0; tt < 4; tt++){
      int t = wave * 4 + tt;
      const float* cr = ctx + (tokbase + t) * HD + lane * 8;
      float v[8];
      float4 a0 = *(const float4*)cr, a1 = *(const float4*)(cr + 4);
      v[0]=a0.x; v[1]=a0.y; v[2]=a0.z; v[3]=a0.w; v[4]=a1.x; v[5]=a1.y; v[6]=a1.z; v[7]=a1.w;
      *(uint4*)(XaB + ((((cW*16 + t)*64 + k0W)*2) ^ SWZ(t))) = pack8(v);
    }
    #pragma unroll
    for (int c = 0; c < 8; c++){
      f32x4 a = proj_tile(XaA, c, qT + ((size_t)c*64 + d)*64, lr, lg);
      float bq = b_q[c*64 + d];
      qp2[c] = packbf4((a[0]+bq)*QSCALE, (a[1]+bq)*QSCALE, (a[2]+bq)*QSCALE, (a[3]+bq)*QSCALE);
    }
  }
  __syncthreads();                                           // B_E

  // ---------------- phase 8: kv proj (XaB=ctx) -> regs; attention #2 -> XaA ----------------
  {
    uint2 kp[8], vp[8];
    #pragma unroll
    for (int c = 0; c < 8; c++){
      const int abase = (c*16 + lr)*128;
      s16x8 af0 = *(const s16x8*)(XaB + ((abase + lg*16) ^ SWZ(lr)));
      s16x8 af1 = *(const s16x8*)(XaB + ((abase + 64 + lg*16) ^ SWZ(lr)));
      const __hip_bfloat16* wr_ = kvT + ((size_t)c*128 + d)*64;
      f32x4 ak = {0.f,0.f,0.f,0.f}, av = ak;
      ak = __builtin_amdgcn_mfma_f32_16x16x32_bf16(af0, *(const s16x8*)((const void*)(wr_ + lg*8)), ak,0,0,0);
      ak = __builtin_amdgcn_mfma_f32_16x16x32_bf16(af1, *(const s16x8*)((const void*)(wr_ + 32 + lg*8)), ak,0,0,0);
      av = __builtin_amdgcn_mfma_f32_16x16x32_bf16(af0, *(const s16x8*)((const void*)(wr_ + 64*64 + lg*8)), av,0,0,0);
      av = __builtin_amdgcn_mfma_f32_16x16x32_bf16(af1, *(const s16x8*)((const void*)(wr_ + 64*64 + 32 + lg*8)), av,0,0,0);
      float bk = b_kv[c*128 + d], bv = b_kv[c*128 + 64 + d];
      kp[c] = packbf4(ak[0]+bk, ak[1]+bk, ak[2]+bk, ak[3]+bk);
      vp[c] = packbf4(av[0]+bv, av[1]+bv, av[2]+bv, av[3]+bv);
    }
    attn_reg(qp2, kp, vp, XaA, wave, lane);
  }
  __syncthreads();                                           // B_F

  // ---------------- phase 10: fc_c -> xca (f32 global) + bf16 stage in XaB ; LN3 stats ----------------
  {
    const __hip_bfloat16* br = fccT + (size_t)d*64;
    const float bb = b_fcc[d];
    float sm[4] = {0.f,0.f,0.f,0.f}, sq[4] = {0.f,0.f,0.f,0.f};
    #pragma unroll
    for (int c = 0; c < 8; c++){
      f32x4 a = proj_tile(XaA, c, br, lr, lg);
      #pragma unroll
      for (int r = 0; r < 4; r++){
        float v = a[r] + bb;
        xca_out[rowbase + (size_t)r*HD + c*64 + d] = v;
        int t = lg*4 + r;
        *(unsigned short*)(XaB + ((((t*512 + c*64 + d)*2)) ^ SWZ(t))) = f2bfu(v);
        sm[r] += v; sq[r] += v*v;
      }
    }
    #pragma unroll
    for (int r = 0; r < 4; r++){
      #pragma unroll
      for (int o = 8; o > 0; o >>= 1){ sm[r] += __shfl_xor(sm[r], o); sq[r] += __shfl_xor(sq[r], o); }
      if (lr == 0){ sred[wave][lg*4+r][0] = sm[r]; sred[wave][lg*4+r][1] = sq[r]; }
    }
  }
  __syncthreads();                                           // B_G

  // ---------------- phase 11: LN3 fused into coalesced flush (reads XaB) ----------------
  {
    const int t2 = tid >> 4, c16 = tid & 15;
    float S = sred[0][t2][0]+sred[1][t2][0]+sred[2][t2][0]+sred[3][t2][0];
    float Q = sred[0][t2][1]+sred[1][t2][1]+sred[2][t2][1]+sred[3][t2][1];
    float mu = S * (1.f/512.f);
    float rs = rsqrtf(Q * (1.f/512.f) - mu*mu + 1e-6f);
    #pragma unroll
    for (int p = 0; p < 4; p++){
      int elem = c16*8 + p*128;
      int byte = (t2*1024 + c16*16 + p*256) ^ SWZ(t2);
      float vv[8];
      unpack8(*(const uint4*)(XaB + byte), vv);
      float4 w0 = *(const float4*)(ln3w + elem), w1 = *(const float4*)(ln3w + elem + 4);
      float4 b0 = *(const float4*)(ln3b + elem), b1 = *(const float4*)(ln3b + elem + 4);
      float nv[8];
      nv[0]=(vv[0]-mu)*rs*w0.x+b0.x; nv[1]=(vv[1]-mu)*rs*w0.y+b0.y;
      nv[2]=(vv[2]-mu)*rs*w0.z+b0.z; nv[3]=(vv[3]-mu)*rs*w0.w+b0.w;
      nv[4]=(vv[4]-mu)*rs*w1.x+b1.x; nv[5]=(vv[5]-mu)*rs*w1.y+b1.y;
      nv[6]=(vv[6]-mu)*rs*w1.z+b1.z; nv[7]=(vv[7]-mu)*rs*w1.w+b1.w;
      *(uint4*)(y_out + (tokbase + t2)*HD + elem) = pack8(nv);
    }
  }
}

// ===== tiled transpose+convert: src[c][K][D] f32 -> dst[c][D][K] bf16 (big weights) =====
__global__ __launch_bounds__(256)
void convT(const float* __restrict__ src, __hip_bfloat16* __restrict__ dst, int K, int D)
{
  const int c = blockIdx.z;
  src += (size_t)c * K * D;
  dst += (size_t)c * D * K;
  __shared__ float tile[32][33];
  const int rb = blockIdx.x * 32, cb = blockIdx.y * 32;
  const int tr = threadIdx.x & 31, tg = threadIdx.x >> 5;
  #pragma unroll
  for (int i = 0; i < 4; i++){
    int r = tg * 4 + i;
    tile[r][tr] = src[(size_t)(rb + r) * D + cb + tr];
  }
  __syncthreads();
  #pragma unroll
  for (int i = 0; i < 4; i++){
    int rr = tg * 4 + i;
    dst[(size_t)(cb + rr) * K + rb + tr] = f2bf(tile[tr][rr]);
  }
}

// ===== one launch for all 5 small weights: K=64 rows each, varying D =====
__global__ __launch_bounds__(256)
void convT_small(const float* __restrict__ w_qkv, const float* __restrict__ w_q,
                 const float* __restrict__ w_kv,  const float* __restrict__ w_fcs,
                 const float* __restrict__ w_fcc,
                 __hip_bfloat16* __restrict__ qkvT, __hip_bfloat16* __restrict__ qT,
                 __hip_bfloat16* __restrict__ kvT,  __hip_bfloat16* __restrict__ fcsT,
                 __hip_bfloat16* __restrict__ fccT)
{
  const int z = blockIdx.z;
  const float* src; __hip_bfloat16* dst; int D, c;
  if      (z <  8){ src = w_qkv; dst = qkvT; D = 192; c = z;      }
  else if (z < 16){ src = w_q;   dst = qT;   D = 64;  c = z - 8;  }
  else if (z < 24){ src = w_kv;  dst = kvT;  D = 128; c = z - 16; }
  else if (z ==24){ src = w_fcs; dst = fcsT; D = 64;  c = 0;      }
  else            { src = w_fcc; dst = fccT; D = 64;  c = 0;      }
  const int cb = blockIdx.y * 32;
  if (cb >= D) return;                       // whole block exits together (pre-barrier)
  src += (size_t)c * 64 * D;
  dst += (size_t)c * D * 64;
  __shared__ float tile[32][33];
  const int rb = blockIdx.x * 32;
  const int tr = threadIdx.x & 31, tg = threadIdx.x >> 5;
  #pragma unroll
  for (int i = 0; i < 4; i++){
    int r = tg * 4 + i;
    tile[r][tr] = src[(size_t)(rb + r) * D + cb + tr];
  }
  __syncthreads();
  #pragma unroll
  for (int i = 0; i < 4; i++){
    int rr = tg * 4 + i;
    dst[(size_t)(cb + rr) * 64 + rb + tr] = f2bf(tile[tr][rr]);
  }
}

// ===== MFMA GEMM (m97 structure, verified rounds 4-10) =====
__device__ __forceinline__ float gelu_exact(float v){
  return 0.5f * v * (1.f + erff(v * 0.70710678118f));
}

template<int EPI>
__global__ __launch_bounds__(256)
void gemm_bt(const __hip_bfloat16* __restrict__ A, const __hip_bfloat16* __restrict__ Bt,
             const float* __restrict__ bias,
             __hip_bfloat16* __restrict__ DstB, float* __restrict__ DstF,
             int M_, int N_, int K_)
{
  __shared__ __align__(16) unsigned char lds[32768];
  unsigned char* As = lds;
  unsigned char* Bs = lds + 16384;

  const int tid = threadIdx.x, lane = tid & 63, wave = tid >> 6;
  const int row0 = blockIdx.x * 128, col0 = blockIdx.y * 128;
  const int lr = lane & 15, lg = lane >> 4;
  const int wr = (wave >> 1) * 64, wc = (wave & 1) * 64;
  const int srow = (lane >> 3), schunk = lane & 7;

  f32x4 acc[4][4];
  #pragma unroll
  for (int i = 0; i < 4; i++)
    #pragma unroll
    for (int j = 0; j < 4; j++)
      acc[i][j] = (f32x4){0.f, 0.f, 0.f, 0.f};

  for (int k0 = 0; k0 < K_; k0 += 64){
    #pragma unroll
    for (int q = 0; q < 4; q++){
      int r  = wave * 32 + q * 8 + srow;
      int ch = schunk ^ (r & 7);
      async16(A  + (size_t)(row0 + r) * K_ + k0 + ch * 8, As + (size_t)(wave*32 + q*8) * 128);
      async16(Bt + (size_t)(col0 + r) * K_ + k0 + ch * 8, Bs + (size_t)(wave*32 + q*8) * 128);
    }
    __syncthreads();

    #pragma unroll
    for (int s = 0; s < 2; s++){
      s16x8 af[4], bfr[4];
      #pragma unroll
      for (int i = 0; i < 4; i++){
        int row = wr + i*16 + lr;
        af[i] = *(const s16x8*)(As + row*128 + ((s*64 + lg*16) ^ ((row & 7) << 4)));
      }
      #pragma unroll
      for (int j = 0; j < 4; j++){
        int row = wc + j*16 + lr;
        bfr[j] = *(const s16x8*)(Bs + row*128 + ((s*64 + lg*16) ^ ((row & 7) << 4)));
      }
      #pragma unroll
      for (int i = 0; i < 4; i++)
        #pragma unroll
        for (int j = 0; j < 4; j++)
          acc[i][j] = __builtin_amdgcn_mfma_f32_16x16x32_bf16(af[i], bfr[j], acc[i][j], 0, 0, 0);
    }
    __syncthreads();
  }

  #pragma unroll
  for (int i = 0; i < 4; i++)
    #pragma unroll
    for (int j = 0; j < 4; j++){
      int col = col0 + wc + j*16 + lr;
      float bc = bias[col];
      #pragma unroll
      for (int r = 0; r < 4; r++){
        int row = row0 + wr + i*16 + lg*4 + r;
        size_t idx = (size_t)row * N_ + col;
        float v = acc[i][j][r] + bc;
        if (EPI == 1) DstB[idx] = f2bf(gelu_exact(v));
        else          DstF[idx] += v;
      }
    }
}

extern "C" void kernel_launch(void* const* d_in, const int* in_sizes, int n_in,
                              void* d_out, int out_size, void* d_ws, size_t ws_size,
                              hipStream_t stream)
{
  const float* x      = (const float*)d_in[0];
  const float* ctx    = (const float*)d_in[1];
  const float* ln1w   = (const float*)d_in[2];
  const float* ln1b   = (const float*)d_in[3];
  const float* w_qkv  = (const float*)d_in[4];
  const float* b_qkv  = (const float*)d_in[5];
  const float* w_fc_s = (const float*)d_in[6];
  const float* b_fc_s = (const float*)d_in[7];
  const float* ln2w   = (const float*)d_in[8];
  const float* ln2b   = (const float*)d_in[9];
  const float* w_q    = (const float*)d_in[10];
  const float* b_q    = (const float*)d_in[11];
  const float* w_kv   = (const float*)d_in[12];
  const float* b_kv   = (const float*)d_in[13];
  const float* w_fc_c = (const float*)d_in[14];
  const float* b_fc_c = (const float*)d_in[15];
  const float* ln3w   = (const float*)d_in[16];
  const float* ln3b   = (const float*)d_in[17];
  const float* w1     = (const float*)d_in[18];
  const float* b1     = (const float*)d_in[19];
  const float* w2     = (const float*)d_in[20];
  const float* b2     = (const float*)d_in[21];

  float* out = (float*)d_out;
  char* wsb = (char*)d_ws;
  __hip_bfloat16* Y   = (__hip_bfloat16*)wsb;                                  // 16 MB
  __hip_bfloat16* mid = (__hip_bfloat16*)(wsb + (size_t)TOKENS*HD*2);          // 64 MB
  __hip_bfloat16* w1t = (__hip_bfloat16*)(wsb + (size_t)TOKENS*HD*2 + (size_t)TOKENS*MM*2);
  __hip_bfloat16* w2t = (__hip_bfloat16*)(wsb + (size_t)TOKENS*HD*2 + (size_t)TOKENS*MM*2 + (size_t)HD*MM*2);

  // small pre-transposed weights live at the head of `mid`: stage_a reads them
  // strictly before gemm1 overwrites mid (stream-ordered, graph-replay safe).
  __hip_bfloat16* qkvT = mid;                 // [8][192][64]
  __hip_bfloat16* qT   = mid + 98304;         // [8][64][64]
  __hip_bfloat16* kvT  = mid + 131072;        // [8][128][64]
  __hip_bfloat16* fcsT = mid + 196608;        // [64][64]
  __hip_bfloat16* fccT = mid + 200704;        // [64][64]

  convT_small<<<dim3(2, 6, 26), 256, 0, stream>>>(w_qkv, w_q, w_kv, w_fc_s, w_fc_c,
                                                  qkvT, qT, kvT, fcsT, fccT);
  convT<<<dim3(16, 64, 1), 256, 0, stream>>>(w1, w1t, HD, MM);
  convT<<<dim3(64, 16, 1), 256, 0, stream>>>(w2, w2t, MM, HD);

  fused_stage_a<<<TOKENS/TB, 256, 0, stream>>>(x, ctx, ln1w, ln1b, qkvT, b_qkv,
                                               fcsT, b_fc_s, ln2w, ln2b, qT, b_q,
                                               kvT, b_kv, fccT, b_fc_c, ln3w, ln3b,
                                               out, Y);

  gemm_bt<1><<<dim3(TOKENS/128, MM/128), 256, 0, stream>>>(Y,   w1t, b1, mid, nullptr, TOKENS, MM, HD);
  gemm_bt<2><<<dim3(TOKENS/128, HD/128), 256, 0, stream>>>(mid, w2t, b2, nullptr, out, TOKENS, HD, MM);
}

// Round 12
// 244.919 us; speedup vs baseline: 1.1330x; 1.1330x over previous
//
#include <hip/hip_runtime.h>
#include <hip/hip_bf16.h>

#define TOKENS (16*1024)
#define HD 512
#define MM 2048
#define TB 16   // tokens per stage_a block

typedef short s16x8 __attribute__((ext_vector_type(8)));
typedef float f32x4 __attribute__((ext_vector_type(4)));

__device__ __forceinline__ __hip_bfloat16 f2bf(float v){ return __float2bfloat16(v); }
__device__ __forceinline__ unsigned short f2bfu(float v){
  __hip_bfloat16 b = __float2bfloat16(v);
  unsigned short u; __builtin_memcpy(&u, &b, 2); return u;
}
__device__ __forceinline__ float bfu2f(unsigned short u){
  unsigned int x = ((unsigned int)u) << 16; float f; __builtin_memcpy(&f, &x, 4); return f;
}
__device__ __forceinline__ float bfx(uint2 p, int r){
  unsigned int u = (r & 2) ? p.y : p.x;
  u = (r & 1) ? (u & 0xffff0000u) : (u << 16);
  float f; __builtin_memcpy(&f, &u, 4); return f;
}
__device__ __forceinline__ uint2 packbf4(float a, float b, float c, float d){
  uint2 o;
  o.x = (unsigned)f2bfu(a) | ((unsigned)f2bfu(b) << 16);
  o.y = (unsigned)f2bfu(c) | ((unsigned)f2bfu(d) << 16);
  return o;
}
__device__ __forceinline__ uint4 pack8(const float* v){
  unsigned short s[8];
  #pragma unroll
  for (int e = 0; e < 8; e++) s[e] = f2bfu(v[e]);
  uint4 u; __builtin_memcpy(&u, s, 16); return u;
}
__device__ __forceinline__ void unpack8(uint4 u, float* v){
  const unsigned short* s = (const unsigned short*)&u;
  #pragma unroll
  for (int e = 0; e < 8; e++) v[e] = bfu2f(s[e]);
}

// async global->LDS, 16B per lane (GEMM staging)
typedef const __attribute__((address_space(1))) unsigned int* gas_t;
typedef __attribute__((address_space(3))) unsigned int* las_t;
__device__ __forceinline__ void async16(const void* g, void* l){
  __builtin_amdgcn_global_load_lds((gas_t)g, (las_t)l, 16, 0, 0);
}

#define SWZ(t) (((t) & 7) << 4)             // Xa byte-address swizzle
#define QSCALE 0.18033688011112042f         // 0.125 * log2(e)

// ---- register-resident 8x8 criss-cross attention; writes result (bf16) to Xa dst ----
__device__ __forceinline__ void attn_reg(const uint2* qp, const uint2* kp, const uint2* vp,
                                         unsigned char* XaDst, int wave, int lane)
{
  const int lr = lane & 15, lg = lane >> 4;
  #pragma unroll
  for (int r = 0; r < 4; r++){
    const int t = lg*4 + r;
    float qq[8], kk[8], vv[8];
    #pragma unroll
    for (int m = 0; m < 8; m++){ qq[m] = bfx(qp[m], r); kk[m] = bfx(kp[m], r); vv[m] = bfx(vp[m], r); }
    float ou[8];
    #pragma unroll
    for (int m = 0; m < 8; m++) ou[m] = 0.f;
    #pragma unroll
    for (int c = 0; c < 8; c++){
      float er[8], den = 0.f;
      #pragma unroll
      for (int m = 0; m < 8; m++){ er[m] = exp2f(qq[c] * kk[m]); den += er[m]; }
      float wc = __fdividef(vv[c], den);
      #pragma unroll
      for (int m = 0; m < 8; m++) ou[m] += wc * er[m];
    }
    #pragma unroll
    for (int m = 0; m < 8; m++){
      int addr = (((m*16 + t)*64 + wave*16 + lr)*2) ^ SWZ(t);
      *(unsigned short*)(XaDst + addr) = f2bfu(ou[m]);
    }
  }
}

// ---- one 16x16 MFMA pair over K=64: A from Xa channel c, B = global bf16 row ----
__device__ __forceinline__ f32x4 proj_tile(const unsigned char* Xa, int c,
                                           const __hip_bfloat16* Brow, int lr, int lg)
{
  const int abase = (c*16 + lr)*128;
  s16x8 af0 = *(const s16x8*)(Xa + ((abase + lg*16) ^ SWZ(lr)));
  s16x8 af1 = *(const s16x8*)(Xa + ((abase + 64 + lg*16) ^ SWZ(lr)));
  s16x8 b0 = *(const s16x8*)((const void*)(Brow + lg*8));
  s16x8 b1 = *(const s16x8*)((const void*)(Brow + 32 + lg*8));
  f32x4 acc = {0.f,0.f,0.f,0.f};
  acc = __builtin_amdgcn_mfma_f32_16x16x32_bf16(af0, b0, acc, 0, 0, 0);
  acc = __builtin_amdgcn_mfma_f32_16x16x32_bf16(af1, b1, acc, 0, 0, 0);
  return acc;
}

// r12: __launch_bounds__(256,3). Ladder: (256,2)=108 VGPR no-spill, 8 waves/CU,
// 115us (r9). (256,4)=64 arch VGPR forced, VALU state can't live in the AGPR
// half -> ~95MB spill, 141us (r10/r11). 3 waves/SIMD gives ~170-reg budget:
// fits ~100 arch + AGPRs with 12 waves/CU.
__global__ __launch_bounds__(256, 3)
void fused_stage_a(const float* __restrict__ x, const float* __restrict__ ctx,
                   const float* __restrict__ ln1w, const float* __restrict__ ln1b,
                   const __hip_bfloat16* __restrict__ qkvT, const float* __restrict__ b_qkv,
                   const __hip_bfloat16* __restrict__ fcsT, const float* __restrict__ b_fcs,
                   const float* __restrict__ ln2w, const float* __restrict__ ln2b,
                   const __hip_bfloat16* __restrict__ qT, const float* __restrict__ b_q,
                   const __hip_bfloat16* __restrict__ kvT, const float* __restrict__ b_kv,
                   const __hip_bfloat16* __restrict__ fccT, const float* __restrict__ b_fcc,
                   const float* __restrict__ ln3w, const float* __restrict__ ln3b,
                   float* __restrict__ xca_out, __hip_bfloat16* __restrict__ y_out)
{
  __shared__ __align__(16) unsigned char XaA[16384];  // [8c][16t][64k] bf16, swizzled
  __shared__ __align__(16) unsigned char XaB[16384];  // attn1 out / ctx / fc_c staging
  __shared__ float sred[4][16][2];

  const int tid = threadIdx.x, lane = tid & 63, wave = tid >> 6;
  const int lr = lane & 15, lg = lane >> 4;
  const int d  = wave*16 + lr;                 // this thread's column slice (within 64)
  const size_t tokbase = (size_t)blockIdx.x * TB;
  const size_t rowbase = (tokbase + lg*4) * HD;
  const int cW = lane >> 3, k0W = (lane & 7) * 8;   // row-loader Xa write slot

  // ---------------- phase 1: LN1(x) -> XaA (vectorized row loads) ----------------
  {
    float lw[8], lb[8];
    {
      float4 w0 = *(const float4*)(ln1w + lane*8), w1 = *(const float4*)(ln1w + lane*8 + 4);
      float4 c0 = *(const float4*)(ln1b + lane*8), c1 = *(const float4*)(ln1b + lane*8 + 4);
      lw[0]=w0.x; lw[1]=w0.y; lw[2]=w0.z; lw[3]=w0.w; lw[4]=w1.x; lw[5]=w1.y; lw[6]=w1.z; lw[7]=w1.w;
      lb[0]=c0.x; lb[1]=c0.y; lb[2]=c0.z; lb[3]=c0.w; lb[4]=c1.x; lb[5]=c1.y; lb[6]=c1.z; lb[7]=c1.w;
    }
    #pragma unroll
    for (int tt = 0; tt < 4; tt++){
      int t = wave * 4 + tt;
      const float* xr = x + (tokbase + t) * HD + lane * 8;
      float v[8];
      float4 a0 = *(const float4*)xr, a1 = *(const float4*)(xr + 4);
      v[0]=a0.x; v[1]=a0.y; v[2]=a0.z; v[3]=a0.w; v[4]=a1.x; v[5]=a1.y; v[6]=a1.z; v[7]=a1.w;
      float sm = 0.f, sq = 0.f;
      #pragma unroll
      for (int e = 0; e < 8; e++){ sm += v[e]; sq += v[e]*v[e]; }
      #pragma unroll
      for (int o = 32; o > 0; o >>= 1){ sm += __shfl_xor(sm, o); sq += __shfl_xor(sq, o); }
      float mu = sm * (1.f/512.f), rs = rsqrtf(sq * (1.f/512.f) - mu*mu + 1e-6f);
      float nv[8];
      #pragma unroll
      for (int e = 0; e < 8; e++) nv[e] = (v[e]-mu)*rs*lw[e] + lb[e];
      *(uint4*)(XaA + ((((cW*16 + t)*64 + k0W)*2) ^ SWZ(t))) = pack8(nv);
    }
  }
  __syncthreads();                                           // B_A

  // ---------------- phase 2: qkv proj -> regs; attention #1 -> XaB ----------------
  {
    uint2 qp[8], kp[8], vp[8];
    #pragma unroll
    for (int c = 0; c < 8; c++){
      const int abase = (c*16 + lr)*128;
      s16x8 af0 = *(const s16x8*)(XaA + ((abase + lg*16) ^ SWZ(lr)));
      s16x8 af1 = *(const s16x8*)(XaA + ((abase + 64 + lg*16) ^ SWZ(lr)));
      const __hip_bfloat16* wr_ = qkvT + ((size_t)c*192 + d)*64;
      f32x4 aq = {0.f,0.f,0.f,0.f}, ak = aq, av = aq;
      aq = __builtin_amdgcn_mfma_f32_16x16x32_bf16(af0, *(const s16x8*)((const void*)(wr_ + lg*8)), aq,0,0,0);
      aq = __builtin_amdgcn_mfma_f32_16x16x32_bf16(af1, *(const s16x8*)((const void*)(wr_ + 32 + lg*8)), aq,0,0,0);
      ak = __builtin_amdgcn_mfma_f32_16x16x32_bf16(af0, *(const s16x8*)((const void*)(wr_ + 64*64 + lg*8)), ak,0,0,0);
      ak = __builtin_amdgcn_mfma_f32_16x16x32_bf16(af1, *(const s16x8*)((const void*)(wr_ + 64*64 + 32 + lg*8)), ak,0,0,0);
      av = __builtin_amdgcn_mfma_f32_16x16x32_bf16(af0, *(const s16x8*)((const void*)(wr_ + 128*64 + lg*8)), av,0,0,0);
      av = __builtin_amdgcn_mfma_f32_16x16x32_bf16(af1, *(const s16x8*)((const void*)(wr_ + 128*64 + 32 + lg*8)), av,0,0,0);
      float bq = b_qkv[c*192 + d], bk = b_qkv[c*192 + 64 + d], bv = b_qkv[c*192 + 128 + d];
      qp[c] = packbf4((aq[0]+bq)*QSCALE, (aq[1]+bq)*QSCALE, (aq[2]+bq)*QSCALE, (aq[3]+bq)*QSCALE);
      kp[c] = packbf4(ak[0]+bk, ak[1]+bk, ak[2]+bk, ak[3]+bk);
      vp[c] = packbf4(av[0]+bv, av[1]+bv, av[2]+bv, av[3]+bv);
    }
    attn_reg(qp, kp, vp, XaB, wave, lane);
  }
  __syncthreads();                                           // B_B

  // ---------------- phase 4: fc_s (XaB) + residual (re-read XaA) + LN2 -> XaA ----------------
  {
    f32x4 fs[8];
    const __hip_bfloat16* br = fcsT + (size_t)d*64;
    const float bb = b_fcs[d];
    #pragma unroll
    for (int c = 0; c < 8; c++) fs[c] = proj_tile(XaB, c, br, lr, lg);
    float val[8][4];
    #pragma unroll
    for (int c = 0; c < 8; c++)
      #pragma unroll
      for (int r = 0; r < 4; r++){
        int t = lg*4 + r;
        float xin = bfu2f(*(const unsigned short*)(XaA + ((((c*16 + t)*64 + d)*2) ^ SWZ(t))));
        val[c][r] = fs[c][r] + bb + xin;
      }
    float lw[8], lb[8];
    #pragma unroll
    for (int c = 0; c < 8; c++){ lw[c] = ln2w[c*64 + d]; lb[c] = ln2b[c*64 + d]; }
    #pragma unroll
    for (int r = 0; r < 4; r++){
      float sm = 0.f, sq = 0.f;
      #pragma unroll
      for (int c = 0; c < 8; c++){ sm += val[c][r]; sq += val[c][r]*val[c][r]; }
      #pragma unroll
      for (int o = 8; o > 0; o >>= 1){ sm += __shfl_xor(sm, o); sq += __shfl_xor(sq, o); }
      if (lr == 0){ sred[wave][lg*4+r][0] = sm; sred[wave][lg*4+r][1] = sq; }
    }
    __syncthreads();                                         // B_C
    #pragma unroll
    for (int r = 0; r < 4; r++){
      int t = lg*4 + r;
      float S = sred[0][t][0]+sred[1][t][0]+sred[2][t][0]+sred[3][t][0];
      float Q = sred[0][t][1]+sred[1][t][1]+sred[2][t][1]+sred[3][t][1];
      float mu = S * (1.f/512.f);
      float rs = rsqrtf(Q * (1.f/512.f) - mu*mu + 1e-6f);
      #pragma unroll
      for (int c = 0; c < 8; c++)
        *(unsigned short*)(XaA + ((((c*16 + t)*64 + d)*2) ^ SWZ(t))) =
            f2bfu((val[c][r]-mu)*rs*lw[c] + lb[c]);
    }
  }
  __syncthreads();                                           // B_D

  // ---------------- phase 6: ctx -> XaB (XaB free post-B_D) ; then q proj -> regs ----------------
  uint2 qp2[8];
  {
    #pragma unroll
    for (int tt = 0; tt < 4; tt++){
      int t = wave * 4 + tt;
      const float* cr = ctx + (tokbase + t) * HD + lane * 8;
      float v[8];
      float4 a0 = *(const float4*)cr, a1 = *(const float4*)(cr + 4);
      v[0]=a0.x; v[1]=a0.y; v[2]=a0.z; v[3]=a0.w; v[4]=a1.x; v[5]=a1.y; v[6]=a1.z; v[7]=a1.w;
      *(uint4*)(XaB + ((((cW*16 + t)*64 + k0W)*2) ^ SWZ(t))) = pack8(v);
    }
    #pragma unroll
    for (int c = 0; c < 8; c++){
      f32x4 a = proj_tile(XaA, c, qT + ((size_t)c*64 + d)*64, lr, lg);
      float bq = b_q[c*64 + d];
      qp2[c] = packbf4((a[0]+bq)*QSCALE, (a[1]+bq)*QSCALE, (a[2]+bq)*QSCALE, (a[3]+bq)*QSCALE);
    }
  }
  __syncthreads();                                           // B_E

  // ---------------- phase 8: kv proj (XaB=ctx) -> regs; attention #2 -> XaA ----------------
  {
    uint2 kp[8], vp[8];
    #pragma unroll
    for (int c = 0; c < 8; c++){
      const int abase = (c*16 + lr)*128;
      s16x8 af0 = *(const s16x8*)(XaB + ((abase + lg*16) ^ SWZ(lr)));
      s16x8 af1 = *(const s16x8*)(XaB + ((abase + 64 + lg*16) ^ SWZ(lr)));
      const __hip_bfloat16* wr_ = kvT + ((size_t)c*128 + d)*64;
      f32x4 ak = {0.f,0.f,0.f,0.f}, av = ak;
      ak = __builtin_amdgcn_mfma_f32_16x16x32_bf16(af0, *(const s16x8*)((const void*)(wr_ + lg*8)), ak,0,0,0);
      ak = __builtin_amdgcn_mfma_f32_16x16x32_bf16(af1, *(const s16x8*)((const void*)(wr_ + 32 + lg*8)), ak,0,0,0);
      av = __builtin_amdgcn_mfma_f32_16x16x32_bf16(af0, *(const s16x8*)((const void*)(wr_ + 64*64 + lg*8)), av,0,0,0);
      av = __builtin_amdgcn_mfma_f32_16x16x32_bf16(af1, *(const s16x8*)((const void*)(wr_ + 64*64 + 32 + lg*8)), av,0,0,0);
      float bk = b_kv[c*128 + d], bv = b_kv[c*128 + 64 + d];
      kp[c] = packbf4(ak[0]+bk, ak[1]+bk, ak[2]+bk, ak[3]+bk);
      vp[c] = packbf4(av[0]+bv, av[1]+bv, av[2]+bv, av[3]+bv);
    }
    attn_reg(qp2, kp, vp, XaA, wave, lane);
  }
  __syncthreads();                                           // B_F

  // ---------------- phase 10: fc_c -> xca (f32 global) + bf16 stage in XaB ; LN3 stats ----------------
  {
    const __hip_bfloat16* br = fccT + (size_t)d*64;
    const float bb = b_fcc[d];
    float sm[4] = {0.f,0.f,0.f,0.f}, sq[4] = {0.f,0.f,0.f,0.f};
    #pragma unroll
    for (int c = 0; c < 8; c++){
      f32x4 a = proj_tile(XaA, c, br, lr, lg);
      #pragma unroll
      for (int r = 0; r < 4; r++){
        float v = a[r] + bb;
        xca_out[rowbase + (size_t)r*HD + c*64 + d] = v;
        int t = lg*4 + r;
        *(unsigned short*)(XaB + ((((t*512 + c*64 + d)*2)) ^ SWZ(t))) = f2bfu(v);
        sm[r] += v; sq[r] += v*v;
      }
    }
    #pragma unroll
    for (int r = 0; r < 4; r++){
      #pragma unroll
      for (int o = 8; o > 0; o >>= 1){ sm[r] += __shfl_xor(sm[r], o); sq[r] += __shfl_xor(sq[r], o); }
      if (lr == 0){ sred[wave][lg*4+r][0] = sm[r]; sred[wave][lg*4+r][1] = sq[r]; }
    }
  }
  __syncthreads();                                           // B_G

  // ---------------- phase 11: LN3 fused into coalesced flush (reads XaB) ----------------
  {
    const int t2 = tid >> 4, c16 = tid & 15;
    float S = sred[0][t2][0]+sred[1][t2][0]+sred[2][t2][0]+sred[3][t2][0];
    float Q = sred[0][t2][1]+sred[1][t2][1]+sred[2][t2][1]+sred[3][t2][1];
    float mu = S * (1.f/512.f);
    float rs = rsqrtf(Q * (1.f/512.f) - mu*mu + 1e-6f);
    #pragma unroll
    for (int p = 0; p < 4; p++){
      int elem = c16*8 + p*128;
      int byte = (t2*1024 + c16*16 + p*256) ^ SWZ(t2);
      float vv[8];
      unpack8(*(const uint4*)(XaB + byte), vv);
      float4 w0 = *(const float4*)(ln3w + elem), w1 = *(const float4*)(ln3w + elem + 4);
      float4 b0 = *(const float4*)(ln3b + elem), b1 = *(const float4*)(ln3b + elem + 4);
      float nv[8];
      nv[0]=(vv[0]-mu)*rs*w0.x+b0.x; nv[1]=(vv[1]-mu)*rs*w0.y+b0.y;
      nv[2]=(vv[2]-mu)*rs*w0.z+b0.z; nv[3]=(vv[3]-mu)*rs*w0.w+b0.w;
      nv[4]=(vv[4]-mu)*rs*w1.x+b1.x; nv[5]=(vv[5]-mu)*rs*w1.y+b1.y;
      nv[6]=(vv[6]-mu)*rs*w1.z+b1.z; nv[7]=(vv[7]-mu)*rs*w1.w+b1.w;
      *(uint4*)(y_out + (tokbase + t2)*HD + elem) = pack8(nv);
    }
  }
}

// ===== tiled transpose+convert: src[c][K][D] f32 -> dst[c][D][K] bf16 (big weights) =====
__global__ __launch_bounds__(256)
void convT(const float* __restrict__ src, __hip_bfloat16* __restrict__ dst, int K, int D)
{
  const int c = blockIdx.z;
  src += (size_t)c * K * D;
  dst += (size_t)c * D * K;
  __shared__ float tile[32][33];
  const int rb = blockIdx.x * 32, cb = blockIdx.y * 32;
  const int tr = threadIdx.x & 31, tg = threadIdx.x >> 5;
  #pragma unroll
  for (int i = 0; i < 4; i++){
    int r = tg * 4 + i;
    tile[r][tr] = src[(size_t)(rb + r) * D + cb + tr];
  }
  __syncthreads();
  #pragma unroll
  for (int i = 0; i < 4; i++){
    int rr = tg * 4 + i;
    dst[(size_t)(cb + rr) * K + rb + tr] = f2bf(tile[tr][rr]);
  }
}

// ===== one launch for all 5 small weights: K=64 rows each, varying D =====
__global__ __launch_bounds__(256)
void convT_small(const float* __restrict__ w_qkv, const float* __restrict__ w_q,
                 const float* __restrict__ w_kv,  const float* __restrict__ w_fcs,
                 const float* __restrict__ w_fcc,
                 __hip_bfloat16* __restrict__ qkvT, __hip_bfloat16* __restrict__ qT,
                 __hip_bfloat16* __restrict__ kvT,  __hip_bfloat16* __restrict__ fcsT,
                 __hip_bfloat16* __restrict__ fccT)
{
  const int z = blockIdx.z;
  const float* src; __hip_bfloat16* dst; int D, c;
  if      (z <  8){ src = w_qkv; dst = qkvT; D = 192; c = z;      }
  else if (z < 16){ src = w_q;   dst = qT;   D = 64;  c = z - 8;  }
  else if (z < 24){ src = w_kv;  dst = kvT;  D = 128; c = z - 16; }
  else if (z ==24){ src = w_fcs; dst = fcsT; D = 64;  c = 0;      }
  else            { src = w_fcc; dst = fccT; D = 64;  c = 0;      }
  const int cb = blockIdx.y * 32;
  if (cb >= D) return;                       // whole block exits together (pre-barrier)
  src += (size_t)c * 64 * D;
  dst += (size_t)c * D * 64;
  __shared__ float tile[32][33];
  const int rb = blockIdx.x * 32;
  const int tr = threadIdx.x & 31, tg = threadIdx.x >> 5;
  #pragma unroll
  for (int i = 0; i < 4; i++){
    int r = tg * 4 + i;
    tile[r][tr] = src[(size_t)(rb + r) * D + cb + tr];
  }
  __syncthreads();
  #pragma unroll
  for (int i = 0; i < 4; i++){
    int rr = tg * 4 + i;
    dst[(size_t)(cb + rr) * 64 + rb + tr] = f2bf(tile[tr][rr]);
  }
}

// ===== MFMA GEMM (m97 structure, verified rounds 4-11) =====
__device__ __forceinline__ float gelu_exact(float v){
  return 0.5f * v * (1.f + erff(v * 0.70710678118f));
}

template<int EPI>
__global__ __launch_bounds__(256)
void gemm_bt(const __hip_bfloat16* __restrict__ A, const __hip_bfloat16* __restrict__ Bt,
             const float* __restrict__ bias,
             __hip_bfloat16* __restrict__ DstB, float* __restrict__ DstF,
             int M_, int N_, int K_)
{
  __shared__ __align__(16) unsigned char lds[32768];
  unsigned char* As = lds;
  unsigned char* Bs = lds + 16384;

  const int tid = threadIdx.x, lane = tid & 63, wave = tid >> 6;
  const int row0 = blockIdx.x * 128, col0 = blockIdx.y * 128;
  const int lr = lane & 15, lg = lane >> 4;
  const int wr = (wave >> 1) * 64, wc = (wave & 1) * 64;
  const int srow = (lane >> 3), schunk = lane & 7;

  f32x4 acc[4][4];
  #pragma unroll
  for (int i = 0; i < 4; i++)
    #pragma unroll
    for (int j = 0; j < 4; j++)
      acc[i][j] = (f32x4){0.f, 0.f, 0.f, 0.f};

  for (int k0 = 0; k0 < K_; k0 += 64){
    #pragma unroll
    for (int q = 0; q < 4; q++){
      int r  = wave * 32 + q * 8 + srow;
      int ch = schunk ^ (r & 7);
      async16(A  + (size_t)(row0 + r) * K_ + k0 + ch * 8, As + (size_t)(wave*32 + q*8) * 128);
      async16(Bt + (size_t)(col0 + r) * K_ + k0 + ch * 8, Bs + (size_t)(wave*32 + q*8) * 128);
    }
    __syncthreads();

    #pragma unroll
    for (int s = 0; s < 2; s++){
      s16x8 af[4], bfr[4];
      #pragma unroll
      for (int i = 0; i < 4; i++){
        int row = wr + i*16 + lr;
        af[i] = *(const s16x8*)(As + row*128 + ((s*64 + lg*16) ^ ((row & 7) << 4)));
      }
      #pragma unroll
      for (int j = 0; j < 4; j++){
        int row = wc + j*16 + lr;
        bfr[j] = *(const s16x8*)(Bs + row*128 + ((s*64 + lg*16) ^ ((row & 7) << 4)));
      }
      #pragma unroll
      for (int i = 0; i < 4; i++)
        #pragma unroll
        for (int j = 0; j < 4; j++)
          acc[i][j] = __builtin_amdgcn_mfma_f32_16x16x32_bf16(af[i], bfr[j], acc[i][j], 0, 0, 0);
    }
    __syncthreads();
  }

  #pragma unroll
  for (int i = 0; i < 4; i++)
    #pragma unroll
    for (int j = 0; j < 4; j++){
      int col = col0 + wc + j*16 + lr;
      float bc = bias[col];
      #pragma unroll
      for (int r = 0; r < 4; r++){
        int row = row0 + wr + i*16 + lg*4 + r;
        size_t idx = (size_t)row * N_ + col;
        float v = acc[i][j][r] + bc;
        if (EPI == 1) DstB[idx] = f2bf(gelu_exact(v));
        else          DstF[idx] += v;
      }
    }
}

extern "C" void kernel_launch(void* const* d_in, const int* in_sizes, int n_in,
                              void* d_out, int out_size, void* d_ws, size_t ws_size,
                              hipStream_t stream)
{
  const float* x      = (const float*)d_in[0];
  const float* ctx    = (const float*)d_in[1];
  const float* ln1w   = (const float*)d_in[2];
  const float* ln1b   = (const float*)d_in[3];
  const float* w_qkv  = (const float*)d_in[4];
  const float* b_qkv  = (const float*)d_in[5];
  const float* w_fc_s = (const float*)d_in[6];
  const float* b_fc_s = (const float*)d_in[7];
  const float* ln2w   = (const float*)d_in[8];
  const float* ln2b   = (const float*)d_in[9];
  const float* w_q    = (const float*)d_in[10];
  const float* b_q    = (const float*)d_in[11];
  const float* w_kv   = (const float*)d_in[12];
  const float* b_kv   = (const float*)d_in[13];
  const float* w_fc_c = (const float*)d_in[14];
  const float* b_fc_c = (const float*)d_in[15];
  const float* ln3w   = (const float*)d_in[16];
  const float* ln3b   = (const float*)d_in[17];
  const float* w1     = (const float*)d_in[18];
  const float* b1     = (const float*)d_in[19];
  const float* w2     = (const float*)d_in[20];
  const float* b2     = (const float*)d_in[21];

  float* out = (float*)d_out;
  char* wsb = (char*)d_ws;
  __hip_bfloat16* Y   = (__hip_bfloat16*)wsb;                                  // 16 MB
  __hip_bfloat16* mid = (__hip_bfloat16*)(wsb + (size_t)TOKENS*HD*2);          // 64 MB
  __hip_bfloat16* w1t = (__hip_bfloat16*)(wsb + (size_t)TOKENS*HD*2 + (size_t)TOKENS*MM*2);
  __hip_bfloat16* w2t = (__hip_bfloat16*)(wsb + (size_t)TOKENS*HD*2 + (size_t)TOKENS*MM*2 + (size_t)HD*MM*2);

  // small pre-transposed weights live at the head of `mid`: stage_a reads them
  // strictly before gemm1 overwrites mid (stream-ordered, graph-replay safe).
  __hip_bfloat16* qkvT = mid;                 // [8][192][64]
  __hip_bfloat16* qT   = mid + 98304;         // [8][64][64]
  __hip_bfloat16* kvT  = mid + 131072;        // [8][128][64]
  __hip_bfloat16* fcsT = mid + 196608;        // [64][64]
  __hip_bfloat16* fccT = mid + 200704;        // [64][64]

  convT_small<<<dim3(2, 6, 26), 256, 0, stream>>>(w_qkv, w_q, w_kv, w_fc_s, w_fc_c,
                                                  qkvT, qT, kvT, fcsT, fccT);
  convT<<<dim3(16, 64, 1), 256, 0, stream>>>(w1, w1t, HD, MM);
  convT<<<dim3(64, 16, 1), 256, 0, stream>>>(w2, w2t, MM, HD);

  fused_stage_a<<<TOKENS/TB, 256, 0, stream>>>(x, ctx, ln1w, ln1b, qkvT, b_qkv,
                                               fcsT, b_fc_s, ln2w, ln2b, qT, b_q,
                                               kvT, b_kv, fccT, b_fc_c, ln3w, ln3b,
                                               out, Y);

  gemm_bt<1><<<dim3(TOKENS/128, MM/128), 256, 0, stream>>>(Y,   w1t, b1, mid, nullptr, TOKENS, MM, HD);
  gemm_bt<2><<<dim3(TOKENS/128, HD/128), 256, 0, stream>>>(mid, w2t, b2, nullptr, out, TOKENS, HD, MM);
}